// Round 3
// baseline (1528.088 us; speedup 1.0000x reference)
//
#include <hip/hip_runtime.h>
#include <math.h>

// Problem constants
#define BSZ 8
#define TT 64
#define NN 64
#define FF 256
#define TWW 8
#define NWW 29
#define LL 512
#define NB (BSZ*NWW)      // 232 window-batches
#define OUTC 128
#define CNTF 118784.0f    // NB*LL

// ws layout (float offsets)
#define OFF_PART0 0           // [512][2][256]
#define OFF_SC0   262144
#define OFF_SH0   262400
#define OFF_H     262656      // [8*64*64][256]
#define OFF_XN    8651264     // [8*64*64][256]
#define OFF_OUTP  17039872    // [232*512][128]
#define OFF_PART1 32244224    // [1024][2][128]
#define OFF_SC1   32506368
#define OFF_SH1   32506496

// ---------------- BN0 stats over xc, computed from x with window multiplicity c(t)
__global__ __launch_bounds__(256) void k_stats0(const float* __restrict__ x, float* __restrict__ part0){
    int bt = blockIdx.x;           // bs*64 + t
    int t  = bt & 63;
    int f  = threadIdx.x;
    const float* xp = x + (size_t)bt * NN * FF + f;
    float s = 0.f, s2 = 0.f;
    #pragma unroll 8
    for (int n = 0; n < NN; ++n){ float v = xp[n*FF]; s += v; s2 += v*v; }
    int wmin = (t >= 7) ? ((t - 6) >> 1) : 0;   // ceil((t-7)/2)
    int wmax = t >> 1; if (wmax > 28) wmax = 28;
    float c = (float)(wmax - wmin + 1);
    part0[bt*512 + f]       = c * s;
    part0[bt*512 + 256 + f] = c * s2;
}

__global__ __launch_bounds__(256) void k_fin0(const float* __restrict__ part0,
                                              const float* __restrict__ gamma, const float* __restrict__ beta,
                                              float* __restrict__ ws){
    int f = threadIdx.x;
    float S = 0.f, S2 = 0.f;
    for (int b = 0; b < 512; ++b){ S += part0[b*512 + f]; S2 += part0[b*512 + 256 + f]; }
    float mean = S / CNTF;
    float var  = S2 / CNTF - mean*mean;
    float sc   = gamma[f] * rsqrtf(var + 1e-5f);
    ws[OFF_SC0 + f] = sc;
    ws[OFF_SH0 + f] = beta[f] - mean*sc;
}

// ---------------- H = x@W_map + b_map ; XN = x*sc0 + sh0
__global__ __launch_bounds__(256,2) void k_map(const float* __restrict__ x, const float* __restrict__ Wm,
                                               const float* __restrict__ bm,
                                               const float* __restrict__ sc0, const float* __restrict__ sh0,
                                               float* __restrict__ H, float* __restrict__ XN){
    __shared__ float xs[64*260];
    int bt  = blockIdx.x;
    int tid = threadIdx.x;
    size_t base = (size_t)bt * NN * FF;
    {   // stage x tile + write XN
        int r  = tid >> 2;
        int f0 = (tid & 3) << 6;
        const float* src = x  + base + r*FF + f0;
        float*       dst = XN + base + r*FF + f0;
        #pragma unroll
        for (int it = 0; it < 16; ++it){
            int f = f0 + it*4;
            float4 v  = *(const float4*)(src + it*4);
            float4 sc = *(const float4*)(sc0 + f);
            float4 sh = *(const float4*)(sh0 + f);
            xs[r*260 + f]   = v.x; xs[r*260 + f+1] = v.y;
            xs[r*260 + f+2] = v.z; xs[r*260 + f+3] = v.w;
            float4 o;
            o.x = v.x*sc.x + sh.x; o.y = v.y*sc.y + sh.y;
            o.z = v.z*sc.z + sh.z; o.w = v.w*sc.w + sh.w;
            *(float4*)(dst + it*4) = o;
        }
    }
    __syncthreads();
    int r0 = (tid >> 6) << 4;        // 16-row group
    int c0 = (tid & 63) << 2;        // 4-col group
    float4 bm4 = *(const float4*)(bm + c0);
    float acc[16][4];
    #pragma unroll
    for (int u = 0; u < 16; ++u){ acc[u][0]=bm4.x; acc[u][1]=bm4.y; acc[u][2]=bm4.z; acc[u][3]=bm4.w; }
    #pragma unroll 2
    for (int k = 0; k < 256; ++k){
        float4 wv = *(const float4*)(Wm + k*FF + c0);
        #pragma unroll
        for (int u = 0; u < 16; ++u){
            float xv = xs[(r0+u)*260 + k];   // wave-uniform broadcast
            acc[u][0] += xv*wv.x; acc[u][1] += xv*wv.y;
            acc[u][2] += xv*wv.z; acc[u][3] += xv*wv.w;
        }
    }
    #pragma unroll
    for (int u = 0; u < 16; ++u)
        *(float4*)(H + base + (size_t)(r0+u)*FF + c0) = make_float4(acc[u][0],acc[u][1],acc[u][2],acc[u][3]);
}

// ---------------- fused: S=QK^T, softmax*mask, (P*mask)@XN + XN, @theta -> out_pre
// Lane's S-row slice: m = g*256 + 4*lane + j  (g=0..1, j=0..3)  -> float4 K reads.
__global__ __launch_bounds__(512,4) void k_attn(const float* __restrict__ H, const float* __restrict__ XN,
                                                const float* __restrict__ theta, const float* __restrict__ thb,
                                                float* __restrict__ outp){
    __shared__ float smem[16384];   // 64KB, phase-reused
    // XCD-aware remap (bijective: 3712 = 8 XCDs * 464): each XCD owns 29
    // consecutive window-batches so H/XN slabs stay in one L2.
    int i    = blockIdx.x;
    int k_   = i >> 3;              // 0..463
    int bw   = (i & 7) * 29 + (k_ >> 4);   // window-batch 0..231
    int tile = k_ & 15;             // 32-row tile 0..15
    int bs   = bw / NWW;
    int w    = bw - bs*NWW;
    const float* Hs  = H  + (size_t)(bs*TT + w*2) * NN * FF;   // contiguous [512][256] slab
    const float* XNs = XN + (size_t)(bs*TT + w*2) * NN * FF;
    int tid = threadIdx.x, lane = tid & 63, wid = tid >> 6;
    int ql = wid << 2;              // this wave's 4 rows for QK / theta phases

    // stage qT[256][32], row-slot swizzled by (f>>4)&7 to kill write bank conflicts
    {
        int r  = tid >> 4;             // 0..31
        int cc = tid & 15;
        int f0 = cc << 4;
        int rs = r ^ ((cc & 7) << 2);  // swizzled slot
        const float* src = Hs + (size_t)(tile*32 + r)*FF + f0;
        #pragma unroll
        for (int i2 = 0; i2 < 16; i2 += 4){
            float4 v = *(const float4*)(src + i2);
            smem[(f0+i2  )*32 + rs] = v.x;
            smem[(f0+i2+1)*32 + rs] = v.y;
            smem[(f0+i2+2)*32 + rs] = v.z;
            smem[(f0+i2+3)*32 + rs] = v.w;
        }
    }
    __syncthreads();

    float sacc[4][8];   // [row li][g*4+j], m = g*256 + 4*lane + j
    #pragma unroll
    for (int a = 0; a < 4; ++a)
        #pragma unroll
        for (int b = 0; b < 8; ++b) sacc[a][b] = 0.f;

    float* kb = smem + 8192;   // kb[16][512], col = m ^ ((kr>>1)<<2)
    int mlo = lane << 2;
    for (int c = 0; c < 16; ++c){
        int k0 = c << 4;
        int qcol = ql ^ ((c & 7) << 2);   // qT swizzle: constant per chunk
        {   // stage kb: thread loads float4 (4 k at one m), scatters to 4 k-rows
            int m0   = tid >> 2;
            int koff = (tid & 3) << 2;
            #pragma unroll
            for (int mi = 0; mi < 4; ++mi){
                int m = m0 + (mi << 7);
                float4 v = *(const float4*)(Hs + (size_t)m*FF + k0 + koff);
                kb[(koff  )*512 + (m ^ (((koff  )>>1)<<2))] = v.x;
                kb[(koff+1)*512 + (m ^ (((koff+1)>>1)<<2))] = v.y;
                kb[(koff+2)*512 + (m ^ (((koff+2)>>1)<<2))] = v.z;
                kb[(koff+3)*512 + (m ^ (((koff+3)>>1)<<2))] = v.w;
            }
        }
        __syncthreads();
        #pragma unroll
        for (int kr = 0; kr < 16; ++kr){
            int s = (kr >> 1) << 2;
            float4 q = *(const float4*)&smem[(k0+kr)*32 + qcol];     // broadcast
            const float* kbr = kb + kr*512;
            float4 ka = *(const float4*)&kbr[mlo ^ s];          // m = 4*lane+j
            float4 kc = *(const float4*)&kbr[256 + (mlo ^ s)];  // m = 256+4*lane+j
            sacc[0][0]+=q.x*ka.x; sacc[0][1]+=q.x*ka.y; sacc[0][2]+=q.x*ka.z; sacc[0][3]+=q.x*ka.w;
            sacc[1][0]+=q.y*ka.x; sacc[1][1]+=q.y*ka.y; sacc[1][2]+=q.y*ka.z; sacc[1][3]+=q.y*ka.w;
            sacc[2][0]+=q.z*ka.x; sacc[2][1]+=q.z*ka.y; sacc[2][2]+=q.z*ka.z; sacc[2][3]+=q.z*ka.w;
            sacc[3][0]+=q.w*ka.x; sacc[3][1]+=q.w*ka.y; sacc[3][2]+=q.w*ka.z; sacc[3][3]+=q.w*ka.w;
            sacc[0][4]+=q.x*kc.x; sacc[0][5]+=q.x*kc.y; sacc[0][6]+=q.x*kc.z; sacc[0][7]+=q.x*kc.w;
            sacc[1][4]+=q.y*kc.x; sacc[1][5]+=q.y*kc.y; sacc[1][6]+=q.y*kc.z; sacc[1][7]+=q.y*kc.w;
            sacc[2][4]+=q.z*kc.x; sacc[2][5]+=q.z*kc.y; sacc[2][6]+=q.z*kc.z; sacc[2][7]+=q.z*kc.w;
            sacc[3][4]+=q.w*kc.x; sacc[3][5]+=q.w*kc.y; sacc[3][6]+=q.w*kc.z; sacc[3][7]+=q.w*kc.w;
        }
        __syncthreads();
    }

    // softmax (registers; row spread over 64 lanes, 8 m each)
    int lbase = tile*32 + ql;
    int twl   = lbase >> 6;                      // uniform across li (lbase 4-aligned)
    const float LOG2D = -0.5145731728297583f;    // log2(0.7)
    float dm0 = exp2f(LOG2D * fabsf((float)(twl - (lane >> 4))));
    float dm1 = exp2f(LOG2D * fabsf((float)(twl - 4 - (lane >> 4))));
    #pragma unroll
    for (int li = 0; li < 4; ++li){
        int lg = lbase + li;
        #pragma unroll
        for (int jj = 0; jj < 8; ++jj){
            float v = sacc[li][jj];
            int m = ((jj >> 2) << 8) + mlo + (jj & 3);
            if (m == lg) v -= 1e8f;               // -eye*1e8
            v = (v > 0.f) ? v : 0.01f*v;          // leaky_relu
            sacc[li][jj] = v;
        }
        float mx = sacc[li][0];
        #pragma unroll
        for (int jj = 1; jj < 8; ++jj) mx = fmaxf(mx, sacc[li][jj]);
        #pragma unroll
        for (int off = 32; off >= 1; off >>= 1) mx = fmaxf(mx, __shfl_xor(mx, off, 64));
        float sum = 0.f;
        #pragma unroll
        for (int jj = 0; jj < 8; ++jj){ float e = __expf(sacc[li][jj] - mx); sacc[li][jj] = e; sum += e; }
        #pragma unroll
        for (int off = 32; off >= 1; off >>= 1) sum += __shfl_xor(sum, off, 64);
        float inv = 1.f / sum;
        float f0m = inv * dm0, f1m = inv * dm1;
        sacc[li][0]*=f0m; sacc[li][1]*=f0m; sacc[li][2]*=f0m; sacc[li][3]*=f0m;
        sacc[li][4]*=f1m; sacc[li][5]*=f1m; sacc[li][6]*=f1m; sacc[li][7]*=f1m;
    }
    __syncthreads();
    // write pG[32][512], col = m ^ (((r>>2)&7)<<2); wave owns rows ql..ql+3.
    // Per store: 64 lanes write one contiguous (XOR-permuted) 1KB stripe — conflict-free.
    {
        int s = wid << 2;                        // ((ql+li)>>2)&7 == wid
        #pragma unroll
        for (int li = 0; li < 4; ++li){
            float* row = smem + (ql+li)*512;
            *(float4*)&row[mlo ^ s]         = make_float4(sacc[li][0],sacc[li][1],sacc[li][2],sacc[li][3]);
            *(float4*)&row[256 + (mlo ^ s)] = make_float4(sacc[li][4],sacc[li][5],sacc[li][6],sacc[li][7]);
        }
    }
    __syncthreads();

    // PV, f-split across waves: wave wid owns f in [32*wid, 32*wid+32).
    // lane: f0 = wid*32 + (lane&7)*4, rows r0 = (lane>>3)*4 (r0 doubles as pG swizzle).
    // Each XN row is read ONCE per block; pG reads are 8-quad broadcasts (conflict-free).
    float acc2[4][4];
    #pragma unroll
    for (int a = 0; a < 4; ++a){ acc2[a][0]=0.f; acc2[a][1]=0.f; acc2[a][2]=0.f; acc2[a][3]=0.f; }
    int f0 = (wid << 5) + ((lane & 7) << 2);
    int r0 = (lane >> 3) << 2;
    const float* xnf = XNs + f0;
    #pragma unroll 2
    for (int mq = 0; mq < 128; ++mq){
        int m0 = mq << 2;
        int cs = m0 ^ r0;
        float4 p0 = *(const float4*)&smem[(r0  )*512 + cs];
        float4 p1 = *(const float4*)&smem[(r0+1)*512 + cs];
        float4 p2 = *(const float4*)&smem[(r0+2)*512 + cs];
        float4 p3 = *(const float4*)&smem[(r0+3)*512 + cs];
        float4 x0 = *(const float4*)(xnf + (size_t)(m0  )*FF);
        float4 x1 = *(const float4*)(xnf + (size_t)(m0+1)*FF);
        float4 x2 = *(const float4*)(xnf + (size_t)(m0+2)*FF);
        float4 x3 = *(const float4*)(xnf + (size_t)(m0+3)*FF);
        acc2[0][0]+=p0.x*x0.x+p0.y*x1.x+p0.z*x2.x+p0.w*x3.x;
        acc2[0][1]+=p0.x*x0.y+p0.y*x1.y+p0.z*x2.y+p0.w*x3.y;
        acc2[0][2]+=p0.x*x0.z+p0.y*x1.z+p0.z*x2.z+p0.w*x3.z;
        acc2[0][3]+=p0.x*x0.w+p0.y*x1.w+p0.z*x2.w+p0.w*x3.w;
        acc2[1][0]+=p1.x*x0.x+p1.y*x1.x+p1.z*x2.x+p1.w*x3.x;
        acc2[1][1]+=p1.x*x0.y+p1.y*x1.y+p1.z*x2.y+p1.w*x3.y;
        acc2[1][2]+=p1.x*x0.z+p1.y*x1.z+p1.z*x2.z+p1.w*x3.z;
        acc2[1][3]+=p1.x*x0.w+p1.y*x1.w+p1.z*x2.w+p1.w*x3.w;
        acc2[2][0]+=p2.x*x0.x+p2.y*x1.x+p2.z*x2.x+p2.w*x3.x;
        acc2[2][1]+=p2.x*x0.y+p2.y*x1.y+p2.z*x2.y+p2.w*x3.y;
        acc2[2][2]+=p2.x*x0.z+p2.y*x1.z+p2.z*x2.z+p2.w*x3.z;
        acc2[2][3]+=p2.x*x0.w+p2.y*x1.w+p2.z*x2.w+p2.w*x3.w;
        acc2[3][0]+=p3.x*x0.x+p3.y*x1.x+p3.z*x2.x+p3.w*x3.x;
        acc2[3][1]+=p3.x*x0.y+p3.y*x1.y+p3.z*x2.y+p3.w*x3.y;
        acc2[3][2]+=p3.x*x0.z+p3.y*x1.z+p3.z*x2.z+p3.w*x3.z;
        acc2[3][3]+=p3.x*x0.w+p3.y*x1.w+p3.z*x2.w+p3.w*x3.w;
    }
    // + identity (A includes +eye, mask diag == 1)
    #pragma unroll
    for (int ri = 0; ri < 4; ++ri){
        float4 xd = *(const float4*)(XNs + (size_t)(tile*32 + r0 + ri)*FF + f0);
        acc2[ri][0]+=xd.x; acc2[ri][1]+=xd.y; acc2[ri][2]+=xd.z; acc2[ri][3]+=xd.w;
    }
    __syncthreads();
    // write axT[256][32] (swizzled): rows r0..r0+3, f = f0..f0+3
    #pragma unroll
    for (int fi = 0; fi < 4; ++fi){
        int f = f0 + fi;
        int col = r0 ^ ((f&7) << 2);
        *(float4*)&smem[(f<<5) + col] = make_float4(acc2[0][fi], acc2[1][fi], acc2[2][fi], acc2[3][fi]);
    }
    __syncthreads();

    // theta GEMM: out_pre[4 rows][2 cols], rows ql..ql+3, o0 = 2*lane
    float oa[4][2];
    #pragma unroll
    for (int a = 0; a < 4; ++a){ oa[a][0]=0.f; oa[a][1]=0.f; }
    const float* thp = theta + (lane << 1);
    #pragma unroll 4
    for (int f = 0; f < 256; ++f){
        int col = ql ^ ((f&7) << 2);
        float4 av = *(const float4*)&smem[(f<<5) + col];  // broadcast: ax[ql..ql+3][f]
        float2 tv = *(const float2*)(thp + f*OUTC);
        oa[0][0]+=av.x*tv.x; oa[0][1]+=av.x*tv.y;
        oa[1][0]+=av.y*tv.x; oa[1][1]+=av.y*tv.y;
        oa[2][0]+=av.z*tv.x; oa[2][1]+=av.z*tv.y;
        oa[3][0]+=av.w*tv.x; oa[3][1]+=av.w*tv.y;
    }
    float2 tb = *(const float2*)(thb + (lane << 1));
    #pragma unroll
    for (int li = 0; li < 4; ++li){
        float2 o; o.x = oa[li][0] + tb.x; o.y = oa[li][1] + tb.y;
        *(float2*)(outp + ((size_t)bw*512 + lbase + li)*OUTC + (lane<<1)) = o;
    }
}

// ---------------- BN1 stats over out_pre (deterministic two-stage)
__global__ __launch_bounds__(256) void k_stats1(const float* __restrict__ outp, float* __restrict__ part1){
    __shared__ float rs[256], rs2[256];
    int tid = threadIdx.x;
    int ch = tid & 127, rh = tid >> 7;
    size_t base = (size_t)blockIdx.x * 116;
    float s = 0.f, s2 = 0.f;
    for (int i = 0; i < 58; ++i){
        float v = outp[(base + rh + 2*i)*128 + ch];
        s += v; s2 += v*v;
    }
    rs[tid] = s; rs2[tid] = s2;
    __syncthreads();
    if (tid < 128){
        part1[blockIdx.x*256 + tid]       = rs[tid] + rs[tid+128];
        part1[blockIdx.x*256 + 128 + tid] = rs2[tid] + rs2[tid+128];
    }
}

__global__ __launch_bounds__(128) void k_fin1(const float* __restrict__ part1,
                                              const float* __restrict__ g1, const float* __restrict__ b1,
                                              float* __restrict__ ws){
    int ch = threadIdx.x;
    float S = 0.f, S2 = 0.f;
    for (int b = 0; b < 1024; ++b){ S += part1[b*256 + ch]; S2 += part1[b*256 + 128 + ch]; }
    float mean = S / CNTF;
    float var  = S2 / CNTF - mean*mean;
    float sc = g1[ch] * rsqrtf(var + 1e-5f);
    ws[OFF_SC1 + ch] = sc;
    ws[OFF_SH1 + ch] = b1[ch] - mean*sc;
}

// ---------------- BN1 apply + leaky + mean-pool over tw
__global__ __launch_bounds__(256) void k_epi(const float* __restrict__ outp,
                                             const float* __restrict__ sc1, const float* __restrict__ sh1,
                                             float* __restrict__ out){
    int idx = blockIdx.x*256 + threadIdx.x;   // < 1900544
    int o = idx & 127;
    int rest = idx >> 7;
    int n = rest & 63;
    int bwq = rest >> 6;                       // bs*29 + w
    float sc = sc1[o], sh = sh1[o];
    size_t rowb = ((size_t)bwq*512 + n)*128 + o;
    float acc = 0.f;
    #pragma unroll
    for (int tw = 0; tw < 8; ++tw){
        float v = outp[rowb + (size_t)tw*64*128];
        v = v*sc + sh;
        v = (v > 0.f) ? v : 0.01f*v;
        acc += v;
    }
    out[idx] = acc * 0.125f;
}

extern "C" void kernel_launch(void* const* d_in, const int* in_sizes, int n_in,
                              void* d_out, int out_size, void* d_ws, size_t ws_size,
                              hipStream_t stream) {
    const float* x   = (const float*)d_in[0];
    const float* Wm  = (const float*)d_in[1];
    const float* bm  = (const float*)d_in[2];
    const float* g0  = (const float*)d_in[3];
    const float* b0  = (const float*)d_in[4];
    const float* th  = (const float*)d_in[5];
    const float* thb = (const float*)d_in[6];
    const float* g1  = (const float*)d_in[7];
    const float* b1  = (const float*)d_in[8];
    float* ws  = (float*)d_ws;
    float* out = (float*)d_out;

    hipLaunchKernelGGL(k_stats0, dim3(512),  dim3(256), 0, stream, x, ws + OFF_PART0);
    hipLaunchKernelGGL(k_fin0,   dim3(1),    dim3(256), 0, stream, ws + OFF_PART0, g0, b0, ws);
    hipLaunchKernelGGL(k_map,    dim3(512),  dim3(256), 0, stream, x, Wm, bm, ws + OFF_SC0, ws + OFF_SH0,
                       ws + OFF_H, ws + OFF_XN);
    hipLaunchKernelGGL(k_attn,   dim3(3712), dim3(512), 0, stream, ws + OFF_H, ws + OFF_XN, th, thb,
                       ws + OFF_OUTP);
    hipLaunchKernelGGL(k_stats1, dim3(1024), dim3(256), 0, stream, ws + OFF_OUTP, ws + OFF_PART1);
    hipLaunchKernelGGL(k_fin1,   dim3(1),    dim3(128), 0, stream, ws + OFF_PART1, g1, b1, ws);
    hipLaunchKernelGGL(k_epi,    dim3(7424), dim3(256), 0, stream, ws + OFF_OUTP, ws + OFF_SC1, ws + OFF_SH1, out);
}

// Round 4
// 831.597 us; speedup vs baseline: 1.8375x; 1.8375x over previous
//
#include <hip/hip_runtime.h>
#include <math.h>

// Problem constants
#define BSZ 8
#define TT 64
#define NN 64
#define FF 256
#define TWW 8
#define NWW 29
#define LL 512
#define NB (BSZ*NWW)      // 232 window-batches
#define OUTC 128
#define CNTF 118784.0f    // NB*LL

typedef unsigned short u16;
typedef float f32x4 __attribute__((ext_vector_type(4)));
typedef __bf16 bf16x8 __attribute__((ext_vector_type(8)));
#define MFMA16(a,b,c) __builtin_amdgcn_mfma_f32_16x16x32_bf16(a,b,c,0,0,0)

// ws layout (BYTE offsets). PART0/PART1 share region 0 (disjoint lifetimes).
#define B_PART  0              // 1 MB: [512][512]f32 then [1024][256]f32
#define B_SC0   1048576        // 256 f32
#define B_SH0   1049600
#define B_SC1   1050624        // 128 f32
#define B_SH1   1051136
#define B_HH    1114112        // u16[32768][256] = 16 MB
#define B_HL    17891328
#define B_XTH   34668544       // u16[256][32768] = 16 MB (transposed XN)
#define B_XTL   51445760
#define B_THH   68222976       // u16[128][256] = 64 KB (theta^T)
#define B_THL   68288512
#define B_OUTP  68354048       // f32[232*512][128] = 60.8 MB (ends 129.2 MB)

static __device__ __forceinline__ u16 f2bf(float v){
    unsigned int u = __float_as_uint(v);
    return (u16)((u + 0x7FFFu + ((u >> 16) & 1u)) >> 16);   // RNE
}
static __device__ __forceinline__ float bf2f(u16 h){
    return __uint_as_float(((unsigned int)h) << 16);
}

// ---------------- BN0 stats over xc, from x with window multiplicity c(t)
__global__ __launch_bounds__(256) void k_stats0(const float* __restrict__ x, float* __restrict__ part0){
    int bt = blockIdx.x;           // bs*64 + t
    int t  = bt & 63;
    int f  = threadIdx.x;
    const float* xp = x + (size_t)bt * NN * FF + f;
    float s = 0.f, s2 = 0.f;
    #pragma unroll 8
    for (int n = 0; n < NN; ++n){ float v = xp[n*FF]; s += v; s2 += v*v; }
    int wmin = (t >= 7) ? ((t - 6) >> 1) : 0;
    int wmax = t >> 1; if (wmax > 28) wmax = 28;
    float c = (float)(wmax - wmin + 1);
    part0[bt*512 + f]       = c * s;
    part0[bt*512 + 256 + f] = c * s2;
}

__global__ __launch_bounds__(256) void k_fin0(const float* __restrict__ part0,
                                              const float* __restrict__ gamma, const float* __restrict__ beta,
                                              float* __restrict__ sc0, float* __restrict__ sh0){
    int f = threadIdx.x;
    float S = 0.f, S2 = 0.f;
    for (int b = 0; b < 512; ++b){ S += part0[b*512 + f]; S2 += part0[b*512 + 256 + f]; }
    float mean = S / CNTF;
    float var  = S2 / CNTF - mean*mean;
    float sc   = gamma[f] * rsqrtf(var + 1e-5f);
    sc0[f] = sc;
    sh0[f] = beta[f] - mean*sc;
}

// ---------------- theta split + transpose: thT[o][f] hi/lo
__global__ __launch_bounds__(256) void k_prep(const float* __restrict__ th,
                                              u16* __restrict__ Th, u16* __restrict__ Tl){
    int idx = blockIdx.x*256 + threadIdx.x;   // 128 blocks -> 32768
    int o = idx >> 8;        // 0..127
    int f = idx & 255;
    float v = th[f*128 + o];
    u16 h = f2bf(v);
    Th[o*256 + f] = h;
    Tl[o*256 + f] = f2bf(v - bf2f(h));
}

// ---------------- H = x@W_map + b_map (split bf16); XNT = (x*sc0+sh0)^T (split bf16)
__global__ __launch_bounds__(256,2) void k_map(const float* __restrict__ x, const float* __restrict__ Wm,
                                               const float* __restrict__ bm,
                                               const float* __restrict__ sc0, const float* __restrict__ sh0,
                                               u16* __restrict__ Hh, u16* __restrict__ Hl,
                                               u16* __restrict__ XTh, u16* __restrict__ XTl){
    __shared__ float xs[64*260];
    int bt  = blockIdx.x;
    int tid = threadIdx.x;
    size_t base = (size_t)bt * NN * FF;
    {   // stage x tile
        int r  = tid >> 2;
        int f0 = (tid & 3) << 6;
        const float* src = x + base + r*FF + f0;
        #pragma unroll
        for (int it = 0; it < 16; ++it){
            int f = f0 + it*4;
            float4 v = *(const float4*)(src + it*4);
            xs[r*260 + f]   = v.x; xs[r*260 + f+1] = v.y;
            xs[r*260 + f+2] = v.z; xs[r*260 + f+3] = v.w;
        }
    }
    __syncthreads();
    // H GEMM (fp32 in regs), then split-store bf16 hi/lo
    int r0 = (tid >> 6) << 4;
    int c0 = (tid & 63) << 2;
    float4 bm4 = *(const float4*)(bm + c0);
    float acc[16][4];
    #pragma unroll
    for (int u = 0; u < 16; ++u){ acc[u][0]=bm4.x; acc[u][1]=bm4.y; acc[u][2]=bm4.z; acc[u][3]=bm4.w; }
    #pragma unroll 2
    for (int k = 0; k < 256; ++k){
        float4 wv = *(const float4*)(Wm + k*FF + c0);
        #pragma unroll
        for (int u = 0; u < 16; ++u){
            float xv = xs[(r0+u)*260 + k];
            acc[u][0] += xv*wv.x; acc[u][1] += xv*wv.y;
            acc[u][2] += xv*wv.z; acc[u][3] += xv*wv.w;
        }
    }
    #pragma unroll
    for (int u = 0; u < 16; ++u){
        size_t idx = base + (size_t)(r0+u)*FF + c0;
        u16 h0=f2bf(acc[u][0]), h1=f2bf(acc[u][1]), h2=f2bf(acc[u][2]), h3=f2bf(acc[u][3]);
        u16 l0=f2bf(acc[u][0]-bf2f(h0)), l1=f2bf(acc[u][1]-bf2f(h1));
        u16 l2=f2bf(acc[u][2]-bf2f(h2)), l3=f2bf(acc[u][3]-bf2f(h3));
        uint2 vh; vh.x = (unsigned)h0 | ((unsigned)h1<<16); vh.y = (unsigned)h2 | ((unsigned)h3<<16);
        uint2 vl; vl.x = (unsigned)l0 | ((unsigned)l1<<16); vl.y = (unsigned)l2 | ((unsigned)l3<<16);
        *(uint2*)(Hh + idx) = vh;
        *(uint2*)(Hl + idx) = vl;
    }
    // XNT: thread owns feature f = tid; write bf16 hi/lo transposed
    {
        int f = tid;
        float sc = sc0[f], sh = sh0[f];
        int gb = bt*64;
        #pragma unroll
        for (int rr = 0; rr < 16; ++rr){
            float v0 = xs[(rr*4+0)*260 + f]*sc + sh;
            float v1 = xs[(rr*4+1)*260 + f]*sc + sh;
            float v2 = xs[(rr*4+2)*260 + f]*sc + sh;
            float v3 = xs[(rr*4+3)*260 + f]*sc + sh;
            u16 h0=f2bf(v0), h1=f2bf(v1), h2=f2bf(v2), h3=f2bf(v3);
            u16 l0=f2bf(v0-bf2f(h0)), l1=f2bf(v1-bf2f(h1)), l2=f2bf(v2-bf2f(h2)), l3=f2bf(v3-bf2f(h3));
            uint2 vh; vh.x = (unsigned)h0 | ((unsigned)h1<<16); vh.y = (unsigned)h2 | ((unsigned)h3<<16);
            uint2 vl; vl.x = (unsigned)l0 | ((unsigned)l1<<16); vl.y = (unsigned)l2 | ((unsigned)l3<<16);
            size_t o = (size_t)f*32768 + gb + rr*4;
            *(uint2*)(XTh + o) = vh;
            *(uint2*)(XTl + o) = vl;
        }
    }
}

// ---------------- fused MFMA attention: S=QK^T, softmax*mask(+eye), P@XN, @theta
// split-bf16 (hi+lo, 3 products) everywhere; fp32 accumulate in MFMA.
__global__ __launch_bounds__(512,4) void k_attn(const u16* __restrict__ Hh, const u16* __restrict__ Hl,
                                                const u16* __restrict__ XTh, const u16* __restrict__ XTl,
                                                const u16* __restrict__ THh, const u16* __restrict__ THl,
                                                const float* __restrict__ thb,
                                                float* __restrict__ outp){
    __shared__ float smem[16384];   // 64KB: S[32][512]f32 -> P_hi/P_lo[32][512]bf16 -> ax_hi/lo[32][256]bf16
    char* sb = (char*)smem;
    // XCD-aware remap (bijective: 3712 = 8 XCDs * 464)
    int i    = blockIdx.x;
    int k_   = i >> 3;
    int bw   = (i & 7) * 29 + (k_ >> 4);
    int tile = k_ & 15;
    int bs   = bw / NWW;
    int w    = bw - bs*NWW;
    int g0   = bs*4096 + w*128;     // window slab base row
    int tid = threadIdx.x, lane = tid & 63, wid = tid >> 6;
    int lr = lane & 15, g = lane >> 4;

    // ---- Phase 1: S = Q K^T via MFMA (A,B direct from global bf16, 16B-contig-K frags)
    const u16* A0h = Hh + (size_t)(g0 + tile*32 + lr)*256;
    const u16* A0l = Hl + (size_t)(g0 + tile*32 + lr)*256;
    const u16* A1h = A0h + 16*256;
    const u16* A1l = A0l + 16*256;
    const u16* Bh0 = Hh + (size_t)(g0 + wid*64 + lr)*256;   // nt = wid*4 + j -> +j*16 rows
    const u16* Bl0 = Hl + (size_t)(g0 + wid*64 + lr)*256;

    f32x4 acc[2][4];
    #pragma unroll
    for (int qt = 0; qt < 2; ++qt)
        #pragma unroll
        for (int j = 0; j < 4; ++j) acc[qt][j] = (f32x4){0.f,0.f,0.f,0.f};

    #pragma unroll
    for (int ks = 0; ks < 8; ++ks){
        int ko = ks*32 + g*8;
        bf16x8 a0h = *(const bf16x8*)(A0h + ko);
        bf16x8 a0l = *(const bf16x8*)(A0l + ko);
        bf16x8 a1h = *(const bf16x8*)(A1h + ko);
        bf16x8 a1l = *(const bf16x8*)(A1l + ko);
        #pragma unroll
        for (int j = 0; j < 4; ++j){
            bf16x8 bh = *(const bf16x8*)(Bh0 + (size_t)j*16*256 + ko);
            bf16x8 bl = *(const bf16x8*)(Bl0 + (size_t)j*16*256 + ko);
            acc[0][j] = MFMA16(a0h, bh, acc[0][j]);
            acc[0][j] = MFMA16(a0h, bl, acc[0][j]);
            acc[0][j] = MFMA16(a0l, bh, acc[0][j]);
            acc[1][j] = MFMA16(a1h, bh, acc[1][j]);
            acc[1][j] = MFMA16(a1h, bl, acc[1][j]);
            acc[1][j] = MFMA16(a1l, bh, acc[1][j]);
        }
    }
    // store S[32][512] f32, byte = (q*2048 + m*4) ^ ((q&7)<<4)
    #pragma unroll
    for (int qt = 0; qt < 2; ++qt)
        #pragma unroll
        for (int j = 0; j < 4; ++j){
            int m = (wid*4 + j)*16 + lr;
            #pragma unroll
            for (int r = 0; r < 4; ++r){
                int q = qt*16 + g*4 + r;
                *(float*)(sb + (((q<<11) + (m<<2)) ^ ((q&7)<<4))) = acc[qt][j][r];
            }
        }
    __syncthreads();

    // ---- Phase 2: softmax * decay (+eye), rows wid*4..+3, lane holds m = 4*lane+jj, 256+4*lane+jj
    float sacc[4][8];
    int mlo = lane << 2;
    int lbase = tile*32 + wid*4;
    int twl   = lbase >> 6;
    const float LOG2D = -0.5145731728297583f;    // log2(0.7)
    float dm0 = exp2f(LOG2D * fabsf((float)(twl - (lane >> 4))));
    float dm1 = exp2f(LOG2D * fabsf((float)(twl - 4 - (lane >> 4))));
    #pragma unroll
    for (int li = 0; li < 4; ++li){
        int q  = wid*4 + li;
        int lg = tile*32 + q;
        int b0 = ((q<<11) + (mlo<<2)) ^ ((q&7)<<4);
        int b1 = ((q<<11) + 1024 + (mlo<<2)) ^ ((q&7)<<4);
        f32x4 s0 = *(const f32x4*)(sb + b0);
        f32x4 s1 = *(const f32x4*)(sb + b1);
        sacc[li][0]=s0[0]; sacc[li][1]=s0[1]; sacc[li][2]=s0[2]; sacc[li][3]=s0[3];
        sacc[li][4]=s1[0]; sacc[li][5]=s1[1]; sacc[li][6]=s1[2]; sacc[li][7]=s1[3];
        #pragma unroll
        for (int jj = 0; jj < 8; ++jj){
            float v = sacc[li][jj];
            int m = ((jj >> 2) << 8) + mlo + (jj & 3);
            if (m == lg) v -= 1e8f;
            v = (v > 0.f) ? v : 0.01f*v;
            sacc[li][jj] = v;
        }
        float mx = sacc[li][0];
        #pragma unroll
        for (int jj = 1; jj < 8; ++jj) mx = fmaxf(mx, sacc[li][jj]);
        #pragma unroll
        for (int off = 32; off >= 1; off >>= 1) mx = fmaxf(mx, __shfl_xor(mx, off, 64));
        float sum = 0.f;
        #pragma unroll
        for (int jj = 0; jj < 8; ++jj){ float e = __expf(sacc[li][jj] - mx); sacc[li][jj] = e; sum += e; }
        #pragma unroll
        for (int off = 32; off >= 1; off >>= 1) sum += __shfl_xor(sum, off, 64);
        float inv = 1.f / sum;
        float f0m = inv * dm0, f1m = inv * dm1;
        sacc[li][0]*=f0m; sacc[li][1]*=f0m; sacc[li][2]*=f0m; sacc[li][3]*=f0m;
        sacc[li][4]*=f1m; sacc[li][5]*=f1m; sacc[li][6]*=f1m; sacc[li][7]*=f1m;
        #pragma unroll
        for (int jj = 0; jj < 8; ++jj){   // + eye (mask diag == 1); softmax diag is exactly 0
            int m = ((jj >> 2) << 8) + mlo + (jj & 3);
            if (m == lg) sacc[li][jj] += 1.0f;
        }
    }
    __syncthreads();   // all waves done reading S

    // write P_hi[32][512]bf16 @0, P_lo @+32KB; byte = (q*1024 + m*2) ^ ((q&7)<<4)
    #pragma unroll
    for (int li = 0; li < 4; ++li){
        int q = wid*4 + li;
        int swz = (q&7) << 4;
        int bA = ((q<<10) + (lane<<3)) ^ swz;          // m = 4*lane..
        int bB = ((q<<10) + 512 + (lane<<3)) ^ swz;    // m = 256+4*lane..
        u16 h[8], l[8];
        #pragma unroll
        for (int jj = 0; jj < 8; ++jj){
            float v = sacc[li][jj];
            h[jj] = f2bf(v);
            l[jj] = f2bf(v - bf2f(h[jj]));
        }
        uint2 vh0; vh0.x=(unsigned)h[0]|((unsigned)h[1]<<16); vh0.y=(unsigned)h[2]|((unsigned)h[3]<<16);
        uint2 vh1; vh1.x=(unsigned)h[4]|((unsigned)h[5]<<16); vh1.y=(unsigned)h[6]|((unsigned)h[7]<<16);
        uint2 vl0; vl0.x=(unsigned)l[0]|((unsigned)l[1]<<16); vl0.y=(unsigned)l[2]|((unsigned)l[3]<<16);
        uint2 vl1; vl1.x=(unsigned)l[4]|((unsigned)l[5]<<16); vl1.y=(unsigned)l[6]|((unsigned)l[7]<<16);
        *(uint2*)(sb + bA)         = vh0;
        *(uint2*)(sb + bB)         = vh1;
        *(uint2*)(sb + 32768 + bA) = vl0;
        *(uint2*)(sb + 32768 + bB) = vl1;
    }
    __syncthreads();   // P ready

    // ---- Phase 3: ax = P @ XN via MFMA (A=P from LDS, B=XNT rows from global)
    const u16* V0h = XTh + (size_t)(wid*32 + lr)*32768 + g0;        // nt = wid*2+jn -> +jn*16 rows
    const u16* V0l = XTl + (size_t)(wid*32 + lr)*32768 + g0;
    f32x4 acc2[2][2];
    #pragma unroll
    for (int qt = 0; qt < 2; ++qt){ acc2[qt][0]=(f32x4){0.f,0.f,0.f,0.f}; acc2[qt][1]=(f32x4){0.f,0.f,0.f,0.f}; }
    #pragma unroll
    for (int ks = 0; ks < 16; ++ks){
        int pb0 = ((lr<<10) + ks*64 + (g<<4)) ^ ((lr&7)<<4);   // q'=lr (qt0); qt1 = +16KB
        bf16x8 p0h = *(const bf16x8*)(sb + pb0);
        bf16x8 p0l = *(const bf16x8*)(sb + 32768 + pb0);
        bf16x8 p1h = *(const bf16x8*)(sb + 16384 + pb0);
        bf16x8 p1l = *(const bf16x8*)(sb + 49152 + pb0);
        int vo = ks*32 + g*8;
        #pragma unroll
        for (int jn = 0; jn < 2; ++jn){
            bf16x8 bh = *(const bf16x8*)(V0h + (size_t)jn*16*32768 + vo);
            bf16x8 bl = *(const bf16x8*)(V0l + (size_t)jn*16*32768 + vo);
            acc2[0][jn] = MFMA16(p0h, bh, acc2[0][jn]);
            acc2[0][jn] = MFMA16(p0h, bl, acc2[0][jn]);
            acc2[0][jn] = MFMA16(p0l, bh, acc2[0][jn]);
            acc2[1][jn] = MFMA16(p1h, bh, acc2[1][jn]);
            acc2[1][jn] = MFMA16(p1h, bl, acc2[1][jn]);
            acc2[1][jn] = MFMA16(p1l, bh, acc2[1][jn]);
        }
    }
    __syncthreads();   // done reading P

    // write ax_hi[32][256]bf16 @0, ax_lo @+16KB; byte = (q*512 + f*2) ^ ((q&7)<<4)
    #pragma unroll
    for (int qt = 0; qt < 2; ++qt)
        #pragma unroll
        for (int jn = 0; jn < 2; ++jn){
            int f = (wid*2 + jn)*16 + lr;
            #pragma unroll
            for (int r = 0; r < 4; ++r){
                int q = qt*16 + g*4 + r;
                float v = acc2[qt][jn][r];
                u16 h = f2bf(v);
                int byte = ((q<<9) + (f<<1)) ^ ((q&7)<<4);
                *(u16*)(sb + byte)         = h;
                *(u16*)(sb + 16384 + byte) = f2bf(v - bf2f(h));
            }
        }
    __syncthreads();   // ax ready

    // ---- Phase 4: out_pre = ax @ theta + thb via MFMA
    const u16* T_h = THh + (size_t)(wid*16 + lr)*256;
    const u16* T_l = THl + (size_t)(wid*16 + lr)*256;
    f32x4 acc3[2];
    acc3[0] = (f32x4){0.f,0.f,0.f,0.f};
    acc3[1] = (f32x4){0.f,0.f,0.f,0.f};
    #pragma unroll
    for (int ks = 0; ks < 8; ++ks){
        int ab0 = ((lr<<9) + ks*64 + (g<<4)) ^ ((lr&7)<<4);
        bf16x8 a0h = *(const bf16x8*)(sb + ab0);
        bf16x8 a0l = *(const bf16x8*)(sb + 16384 + ab0);
        bf16x8 a1h = *(const bf16x8*)(sb + 8192 + ab0);
        bf16x8 a1l = *(const bf16x8*)(sb + 24576 + ab0);
        int to = ks*32 + g*8;
        bf16x8 bh = *(const bf16x8*)(T_h + to);
        bf16x8 bl = *(const bf16x8*)(T_l + to);
        acc3[0] = MFMA16(a0h, bh, acc3[0]);
        acc3[0] = MFMA16(a0h, bl, acc3[0]);
        acc3[0] = MFMA16(a0l, bh, acc3[0]);
        acc3[1] = MFMA16(a1h, bh, acc3[1]);
        acc3[1] = MFMA16(a1h, bl, acc3[1]);
        acc3[1] = MFMA16(a1l, bh, acc3[1]);
    }
    float tb = thb[wid*16 + lr];
    #pragma unroll
    for (int qt = 0; qt < 2; ++qt)
        #pragma unroll
        for (int r = 0; r < 4; ++r){
            int q = qt*16 + g*4 + r;
            size_t R = (size_t)bw*512 + tile*32 + q;
            outp[R*128 + wid*16 + lr] = acc3[qt][r] + tb;
        }
}

// ---------------- BN1 stats over out_pre (deterministic two-stage)
__global__ __launch_bounds__(256) void k_stats1(const float* __restrict__ outp, float* __restrict__ part1){
    __shared__ float rs[256], rs2[256];
    int tid = threadIdx.x;
    int ch = tid & 127, rh = tid >> 7;
    size_t base = (size_t)blockIdx.x * 116;
    float s = 0.f, s2 = 0.f;
    for (int i = 0; i < 58; ++i){
        float v = outp[(base + rh + 2*i)*128 + ch];
        s += v; s2 += v*v;
    }
    rs[tid] = s; rs2[tid] = s2;
    __syncthreads();
    if (tid < 128){
        part1[blockIdx.x*256 + tid]       = rs[tid] + rs[tid+128];
        part1[blockIdx.x*256 + 128 + tid] = rs2[tid] + rs2[tid+128];
    }
}

__global__ __launch_bounds__(128) void k_fin1(const float* __restrict__ part1,
                                              const float* __restrict__ g1, const float* __restrict__ b1,
                                              float* __restrict__ sc1, float* __restrict__ sh1){
    int ch = threadIdx.x;
    float S = 0.f, S2 = 0.f;
    for (int b = 0; b < 1024; ++b){ S += part1[b*256 + ch]; S2 += part1[b*256 + 128 + ch]; }
    float mean = S / CNTF;
    float var  = S2 / CNTF - mean*mean;
    float sc = g1[ch] * rsqrtf(var + 1e-5f);
    sc1[ch] = sc;
    sh1[ch] = b1[ch] - mean*sc;
}

// ---------------- BN1 apply + leaky + mean-pool over tw
__global__ __launch_bounds__(256) void k_epi(const float* __restrict__ outp,
                                             const float* __restrict__ sc1, const float* __restrict__ sh1,
                                             float* __restrict__ out){
    int idx = blockIdx.x*256 + threadIdx.x;   // < 1900544
    int o = idx & 127;
    int rest = idx >> 7;
    int n = rest & 63;
    int bwq = rest >> 6;
    float sc = sc1[o], sh = sh1[o];
    size_t rowb = ((size_t)bwq*512 + n)*128 + o;
    float acc = 0.f;
    #pragma unroll
    for (int tw = 0; tw < 8; ++tw){
        float v = outp[rowb + (size_t)tw*64*128];
        v = v*sc + sh;
        v = (v > 0.f) ? v : 0.01f*v;
        acc += v;
    }
    out[idx] = acc * 0.125f;
}

extern "C" void kernel_launch(void* const* d_in, const int* in_sizes, int n_in,
                              void* d_out, int out_size, void* d_ws, size_t ws_size,
                              hipStream_t stream) {
    const float* x   = (const float*)d_in[0];
    const float* Wm  = (const float*)d_in[1];
    const float* bm  = (const float*)d_in[2];
    const float* g0  = (const float*)d_in[3];
    const float* b0  = (const float*)d_in[4];
    const float* th  = (const float*)d_in[5];
    const float* thb = (const float*)d_in[6];
    const float* g1  = (const float*)d_in[7];
    const float* b1  = (const float*)d_in[8];
    char* wsb  = (char*)d_ws;
    float* out = (float*)d_out;

    float* part = (float*)(wsb + B_PART);
    float* sc0  = (float*)(wsb + B_SC0);
    float* sh0  = (float*)(wsb + B_SH0);
    float* sc1  = (float*)(wsb + B_SC1);
    float* sh1  = (float*)(wsb + B_SH1);
    u16* Hh  = (u16*)(wsb + B_HH);
    u16* Hl  = (u16*)(wsb + B_HL);
    u16* XTh = (u16*)(wsb + B_XTH);
    u16* XTl = (u16*)(wsb + B_XTL);
    u16* THh = (u16*)(wsb + B_THH);
    u16* THl = (u16*)(wsb + B_THL);
    float* outp = (float*)(wsb + B_OUTP);

    hipLaunchKernelGGL(k_stats0, dim3(512),  dim3(256), 0, stream, x, part);
    hipLaunchKernelGGL(k_fin0,   dim3(1),    dim3(256), 0, stream, part, g0, b0, sc0, sh0);
    hipLaunchKernelGGL(k_prep,   dim3(128),  dim3(256), 0, stream, th, THh, THl);
    hipLaunchKernelGGL(k_map,    dim3(512),  dim3(256), 0, stream, x, Wm, bm, sc0, sh0, Hh, Hl, XTh, XTl);
    hipLaunchKernelGGL(k_attn,   dim3(3712), dim3(512), 0, stream, Hh, Hl, XTh, XTl, THh, THl, thb, outp);
    hipLaunchKernelGGL(k_stats1, dim3(1024), dim3(256), 0, stream, outp, part);
    hipLaunchKernelGGL(k_fin1,   dim3(1),    dim3(128), 0, stream, part, g1, b1, sc1, sh1);
    hipLaunchKernelGGL(k_epi,    dim3(7424), dim3(256), 0, stream, outp, sc1, sh1, out);
}

// Round 9
// 553.402 us; speedup vs baseline: 2.7613x; 1.5027x over previous
//
#include <hip/hip_runtime.h>
#include <math.h>

// Problem constants
#define BSZ 8
#define TT 64
#define NN 64
#define FF 256
#define TWW 8
#define NWW 29
#define LL 512
#define NB (BSZ*NWW)      // 232 window-batches
#define OUTC 128
#define CNTF 118784.0f    // NB*LL

typedef unsigned short u16;
typedef float f32x4 __attribute__((ext_vector_type(4)));
typedef __bf16 bf16x8 __attribute__((ext_vector_type(8)));
#define MFMA16(a,b,c) __builtin_amdgcn_mfma_f32_16x16x32_bf16(a,b,c,0,0,0)

// Tiled layout strides (u16 elements)
#define HT_FT 1048576ull      // Ht[ft][m][fi]: ft stride = 32768*32
#define XT_MT 8192ull         // XTt[mt][f][mi]: mt stride = 256*32
#define TH_FT 4096ull         // THt[ft][o][fi]: ft stride = 128*32

// ws layout (BYTE offsets). PART0/PART1 share region 0 (disjoint lifetimes).
#define B_PART  0              // 1 MB
#define B_SC0   1048576
#define B_SH0   1049600
#define B_SC1   1050624
#define B_SH1   1051136
#define B_HH    1114112        // u16 Ht_hi [8][32768][32] = 16 MB
#define B_HL    17891328
#define B_XTH   34668544       // u16 XTt_hi [1024][256][32] = 16 MB
#define B_XTL   51445760
#define B_THH   68222976       // u16 THt_hi [8][128][32] = 64 KB
#define B_THL   68288512
#define B_OUTP  68354048       // f32[232*512][128] = 60.8 MB

static __device__ __forceinline__ u16 f2bf(float v){
    unsigned int u = __float_as_uint(v);
    return (u16)((u + 0x7FFFu + ((u >> 16) & 1u)) >> 16);   // RNE
}
static __device__ __forceinline__ float bf2f(u16 h){
    return __uint_as_float(((unsigned int)h) << 16);
}

// ---------------- BN0 stats over xc, from x with window multiplicity c(t)
__global__ __launch_bounds__(256) void k_stats0(const float* __restrict__ x, float* __restrict__ part0){
    int bt = blockIdx.x;           // bs*64 + t
    int t  = bt & 63;
    int f  = threadIdx.x;
    const float* xp = x + (size_t)bt * NN * FF + f;
    float s = 0.f, s2 = 0.f;
    #pragma unroll 8
    for (int n = 0; n < NN; ++n){ float v = xp[n*FF]; s += v; s2 += v*v; }
    int wmin = (t >= 7) ? ((t - 6) >> 1) : 0;
    int wmax = t >> 1; if (wmax > 28) wmax = 28;
    float c = (float)(wmax - wmin + 1);
    part0[bt*512 + f]       = c * s;
    part0[bt*512 + 256 + f] = c * s2;
}

__global__ __launch_bounds__(256) void k_fin0(const float* __restrict__ part0,
                                              const float* __restrict__ gamma, const float* __restrict__ beta,
                                              float* __restrict__ sc0, float* __restrict__ sh0){
    int f = threadIdx.x;
    float S = 0.f, S2 = 0.f;
    for (int b = 0; b < 512; ++b){ S += part0[b*512 + f]; S2 += part0[b*512 + 256 + f]; }
    float mean = S / CNTF;
    float var  = S2 / CNTF - mean*mean;
    float sc   = gamma[f] * rsqrtf(var + 1e-5f);
    sc0[f] = sc;
    sh0[f] = beta[f] - mean*sc;
}

// ---------------- theta split + transpose + f-tile: THt[f>>5][o][f&31]
__global__ __launch_bounds__(256) void k_prep(const float* __restrict__ th,
                                              u16* __restrict__ Th, u16* __restrict__ Tl){
    int idx = blockIdx.x*256 + threadIdx.x;   // 128 blocks -> 32768
    int o = idx >> 8;        // 0..127
    int f = idx & 255;
    float v = th[f*128 + o];
    u16 h = f2bf(v);
    size_t a = (size_t)(f>>5)*TH_FT + o*32 + (f&31);
    Th[a] = h;
    Tl[a] = f2bf(v - bf2f(h));
}

// ---------------- H = x@W_map + b_map -> Ht (f-tiled, split bf16);
//                  XNT = (x*sc0+sh0) -> XTt (m-tiled transposed, split bf16)
__global__ __launch_bounds__(256,2) void k_map(const float* __restrict__ x, const float* __restrict__ Wm,
                                               const float* __restrict__ bm,
                                               const float* __restrict__ sc0, const float* __restrict__ sh0,
                                               u16* __restrict__ Hh, u16* __restrict__ Hl,
                                               u16* __restrict__ XTh, u16* __restrict__ XTl){
    __shared__ float xs[64*260];
    int bt  = blockIdx.x;
    int tid = threadIdx.x;
    size_t base = (size_t)bt * NN * FF;
    {   // stage x tile
        int r  = tid >> 2;
        int f0 = (tid & 3) << 6;
        const float* src = x + base + r*FF + f0;
        #pragma unroll
        for (int it = 0; it < 16; ++it){
            int f = f0 + it*4;
            float4 v = *(const float4*)(src + it*4);
            xs[r*260 + f]   = v.x; xs[r*260 + f+1] = v.y;
            xs[r*260 + f+2] = v.z; xs[r*260 + f+3] = v.w;
        }
    }
    __syncthreads();
    // H GEMM (fp32 in regs), split-store bf16 hi/lo to tiled layout
    int r0 = (tid >> 6) << 4;
    int c0 = (tid & 63) << 2;
    float4 bm4 = *(const float4*)(bm + c0);
    float acc[16][4];
    #pragma unroll
    for (int u = 0; u < 16; ++u){ acc[u][0]=bm4.x; acc[u][1]=bm4.y; acc[u][2]=bm4.z; acc[u][3]=bm4.w; }
    #pragma unroll 2
    for (int k = 0; k < 256; ++k){
        float4 wv = *(const float4*)(Wm + k*FF + c0);
        #pragma unroll
        for (int u = 0; u < 16; ++u){
            float xv = xs[(r0+u)*260 + k];
            acc[u][0] += xv*wv.x; acc[u][1] += xv*wv.y;
            acc[u][2] += xv*wv.z; acc[u][3] += xv*wv.w;
        }
    }
    size_t hbase = (size_t)(c0>>5)*HT_FT + (c0&31);
    #pragma unroll
    for (int u = 0; u < 16; ++u){
        size_t idx = hbase + (size_t)(bt*64 + r0 + u)*32;
        u16 h0=f2bf(acc[u][0]), h1=f2bf(acc[u][1]), h2=f2bf(acc[u][2]), h3=f2bf(acc[u][3]);
        u16 l0=f2bf(acc[u][0]-bf2f(h0)), l1=f2bf(acc[u][1]-bf2f(h1));
        u16 l2=f2bf(acc[u][2]-bf2f(h2)), l3=f2bf(acc[u][3]-bf2f(h3));
        uint2 vh; vh.x = (unsigned)h0 | ((unsigned)h1<<16); vh.y = (unsigned)h2 | ((unsigned)h3<<16);
        uint2 vl; vl.x = (unsigned)l0 | ((unsigned)l1<<16); vl.y = (unsigned)l2 | ((unsigned)l3<<16);
        *(uint2*)(Hh + idx) = vh;
        *(uint2*)(Hl + idx) = vl;
    }
    // XNT: thread owns feature f = tid; write bf16 hi/lo into m-tiled transpose
    {
        int f = tid;
        float sc = sc0[f], sh = sh0[f];
        #pragma unroll
        for (int rr = 0; rr < 16; ++rr){
            int n = rr*4;
            float v0 = xs[(n  )*260 + f]*sc + sh;
            float v1 = xs[(n+1)*260 + f]*sc + sh;
            float v2 = xs[(n+2)*260 + f]*sc + sh;
            float v3 = xs[(n+3)*260 + f]*sc + sh;
            u16 h0=f2bf(v0), h1=f2bf(v1), h2=f2bf(v2), h3=f2bf(v3);
            u16 l0=f2bf(v0-bf2f(h0)), l1=f2bf(v1-bf2f(h1)), l2=f2bf(v2-bf2f(h2)), l3=f2bf(v3-bf2f(h3));
            uint2 vh; vh.x = (unsigned)h0 | ((unsigned)h1<<16); vh.y = (unsigned)h2 | ((unsigned)h3<<16);
            uint2 vl; vl.x = (unsigned)l0 | ((unsigned)l1<<16); vl.y = (unsigned)l2 | ((unsigned)l3<<16);
            size_t o = (size_t)(bt*2 + (n>>5))*XT_MT + f*32 + (n&31);
            *(uint2*)(XTh + o) = vh;
            *(uint2*)(XTl + o) = vl;
        }
    }
}

// ---------------- fused MFMA attention: S=QK^T, softmax*mask(+eye), P@XN, @theta
// All global fragment loads are 1KB wave-coalesced via tiled layouts.
__global__ __launch_bounds__(512,4) void k_attn(const u16* __restrict__ Hh, const u16* __restrict__ Hl,
                                                const u16* __restrict__ XTh, const u16* __restrict__ XTl,
                                                const u16* __restrict__ THh, const u16* __restrict__ THl,
                                                const float* __restrict__ thb,
                                                float* __restrict__ outp){
    __shared__ float smem[16384];   // 64KB: S[32][512]f32 -> P_hi/P_lo bf16 -> ax_hi/lo bf16
    char* sb = (char*)smem;
    // XCD-aware remap (bijective: 3712 = 8 XCDs * 464)
    int i    = blockIdx.x;
    int k_   = i >> 3;
    int bw   = (i & 7) * 29 + (k_ >> 4);
    int tile = k_ & 15;
    int bs   = bw / NWW;
    int w    = bw - bs*NWW;
    int g0   = bs*4096 + w*128;     // window slab base row
    int g032 = bs*128 + w*4;        // g0/32 (m-tile base)
    int tid = threadIdx.x, lane = tid & 63, wid = tid >> 6;
    int lr = lane & 15, g = lane >> 4;

    // ---- Phase 1: S = Q K^T via MFMA; frag loads 1KB-coalesced from Ht
    f32x4 acc[2][4];
    #pragma unroll
    for (int qt = 0; qt < 2; ++qt)
        #pragma unroll
        for (int j = 0; j < 4; ++j) acc[qt][j] = (f32x4){0.f,0.f,0.f,0.f};

    int qrow = g0 + tile*32 + lr;
    int brow = g0 + wid*64 + lr;
    #pragma unroll
    for (int ks = 0; ks < 8; ++ks){
        size_t tb = (size_t)ks*HT_FT + g*8;
        bf16x8 a0h = *(const bf16x8*)(Hh + tb + (size_t)qrow*32);
        bf16x8 a0l = *(const bf16x8*)(Hl + tb + (size_t)qrow*32);
        bf16x8 a1h = *(const bf16x8*)(Hh + tb + (size_t)(qrow+16)*32);
        bf16x8 a1l = *(const bf16x8*)(Hl + tb + (size_t)(qrow+16)*32);
        #pragma unroll
        for (int j = 0; j < 4; ++j){
            size_t mb = tb + (size_t)(brow + j*16)*32;
            bf16x8 bh = *(const bf16x8*)(Hh + mb);
            bf16x8 bl = *(const bf16x8*)(Hl + mb);
            acc[0][j] = MFMA16(a0h, bh, acc[0][j]);
            acc[0][j] = MFMA16(a0h, bl, acc[0][j]);
            acc[0][j] = MFMA16(a0l, bh, acc[0][j]);
            acc[1][j] = MFMA16(a1h, bh, acc[1][j]);
            acc[1][j] = MFMA16(a1h, bl, acc[1][j]);
            acc[1][j] = MFMA16(a1l, bh, acc[1][j]);
        }
    }
    // store S[32][512] f32, byte = (q*2048 + m*4) ^ ((q&7)<<4)
    #pragma unroll
    for (int qt = 0; qt < 2; ++qt)
        #pragma unroll
        for (int j = 0; j < 4; ++j){
            int m = (wid*4 + j)*16 + lr;
            #pragma unroll
            for (int r = 0; r < 4; ++r){
                int q = qt*16 + g*4 + r;
                *(float*)(sb + (((q<<11) + (m<<2)) ^ ((q&7)<<4))) = acc[qt][j][r];
            }
        }
    __syncthreads();

    // ---- Phase 2: softmax * decay (+eye), rows wid*4..+3, lane holds m = 4*lane+jj, 256+4*lane+jj
    float sacc[4][8];
    int mlo = lane << 2;
    int lbase = tile*32 + wid*4;
    int twl   = lbase >> 6;
    const float LOG2D = -0.5145731728297583f;    // log2(0.7)
    float dm0 = exp2f(LOG2D * fabsf((float)(twl - (lane >> 4))));
    float dm1 = exp2f(LOG2D * fabsf((float)(twl - 4 - (lane >> 4))));
    #pragma unroll
    for (int li = 0; li < 4; ++li){
        int q  = wid*4 + li;
        int lg = tile*32 + q;
        int b0 = ((q<<11) + (mlo<<2)) ^ ((q&7)<<4);
        int b1 = ((q<<11) + 1024 + (mlo<<2)) ^ ((q&7)<<4);
        f32x4 s0 = *(const f32x4*)(sb + b0);
        f32x4 s1 = *(const f32x4*)(sb + b1);
        sacc[li][0]=s0[0]; sacc[li][1]=s0[1]; sacc[li][2]=s0[2]; sacc[li][3]=s0[3];
        sacc[li][4]=s1[0]; sacc[li][5]=s1[1]; sacc[li][6]=s1[2]; sacc[li][7]=s1[3];
        #pragma unroll
        for (int jj = 0; jj < 8; ++jj){
            float v = sacc[li][jj];
            int m = ((jj >> 2) << 8) + mlo + (jj & 3);
            if (m == lg) v -= 1e8f;
            v = (v > 0.f) ? v : 0.01f*v;
            sacc[li][jj] = v;
        }
        float mx = sacc[li][0];
        #pragma unroll
        for (int jj = 1; jj < 8; ++jj) mx = fmaxf(mx, sacc[li][jj]);
        #pragma unroll
        for (int off = 32; off >= 1; off >>= 1) mx = fmaxf(mx, __shfl_xor(mx, off, 64));
        float sum = 0.f;
        #pragma unroll
        for (int jj = 0; jj < 8; ++jj){ float e = __expf(sacc[li][jj] - mx); sacc[li][jj] = e; sum += e; }
        #pragma unroll
        for (int off = 32; off >= 1; off >>= 1) sum += __shfl_xor(sum, off, 64);
        float inv = 1.f / sum;
        float f0m = inv * dm0, f1m = inv * dm1;
        sacc[li][0]*=f0m; sacc[li][1]*=f0m; sacc[li][2]*=f0m; sacc[li][3]*=f0m;
        sacc[li][4]*=f1m; sacc[li][5]*=f1m; sacc[li][6]*=f1m; sacc[li][7]*=f1m;
        #pragma unroll
        for (int jj = 0; jj < 8; ++jj){   // + eye (mask diag == 1); softmax diag is exactly 0
            int m = ((jj >> 2) << 8) + mlo + (jj & 3);
            if (m == lg) sacc[li][jj] += 1.0f;
        }
    }
    __syncthreads();   // all waves done reading S

    // write P_hi[32][512]bf16 @0, P_lo @+32KB; byte = (q*1024 + m*2) ^ ((q&7)<<4)
    #pragma unroll
    for (int li = 0; li < 4; ++li){
        int q = wid*4 + li;
        int swz = (q&7) << 4;
        int bA = ((q<<10) + (lane<<3)) ^ swz;
        int bB = ((q<<10) + 512 + (lane<<3)) ^ swz;
        u16 h[8], l[8];
        #pragma unroll
        for (int jj = 0; jj < 8; ++jj){
            float v = sacc[li][jj];
            h[jj] = f2bf(v);
            l[jj] = f2bf(v - bf2f(h[jj]));
        }
        uint2 vh0; vh0.x=(unsigned)h[0]|((unsigned)h[1]<<16); vh0.y=(unsigned)h[2]|((unsigned)h[3]<<16);
        uint2 vh1; vh1.x=(unsigned)h[4]|((unsigned)h[5]<<16); vh1.y=(unsigned)h[6]|((unsigned)h[7]<<16);
        uint2 vl0; vl0.x=(unsigned)l[0]|((unsigned)l[1]<<16); vl0.y=(unsigned)l[2]|((unsigned)l[3]<<16);
        uint2 vl1; vl1.x=(unsigned)l[4]|((unsigned)l[5]<<16); vl1.y=(unsigned)l[6]|((unsigned)l[7]<<16);
        *(uint2*)(sb + bA)         = vh0;
        *(uint2*)(sb + bB)         = vh1;
        *(uint2*)(sb + 32768 + bA) = vl0;
        *(uint2*)(sb + 32768 + bB) = vl1;
    }
    __syncthreads();   // P ready

    // ---- Phase 3: ax = P @ XN via MFMA (A=P from LDS, B=XTt 1KB-coalesced)
    f32x4 acc2[2][2];
    #pragma unroll
    for (int qt = 0; qt < 2; ++qt){ acc2[qt][0]=(f32x4){0.f,0.f,0.f,0.f}; acc2[qt][1]=(f32x4){0.f,0.f,0.f,0.f}; }
    int frow = wid*32 + lr;
    #pragma unroll
    for (int ks = 0; ks < 16; ++ks){
        int pb0 = ((lr<<10) + ks*64 + (g<<4)) ^ ((lr&7)<<4);
        bf16x8 p0h = *(const bf16x8*)(sb + pb0);
        bf16x8 p0l = *(const bf16x8*)(sb + 32768 + pb0);
        bf16x8 p1h = *(const bf16x8*)(sb + 16384 + pb0);
        bf16x8 p1l = *(const bf16x8*)(sb + 49152 + pb0);
        size_t vb = (size_t)(g032 + ks)*XT_MT + g*8;
        #pragma unroll
        for (int jn = 0; jn < 2; ++jn){
            size_t fb = vb + (size_t)(frow + jn*16)*32;
            bf16x8 bh = *(const bf16x8*)(XTh + fb);
            bf16x8 bl = *(const bf16x8*)(XTl + fb);
            acc2[0][jn] = MFMA16(p0h, bh, acc2[0][jn]);
            acc2[0][jn] = MFMA16(p0h, bl, acc2[0][jn]);
            acc2[0][jn] = MFMA16(p0l, bh, acc2[0][jn]);
            acc2[1][jn] = MFMA16(p1h, bh, acc2[1][jn]);
            acc2[1][jn] = MFMA16(p1h, bl, acc2[1][jn]);
            acc2[1][jn] = MFMA16(p1l, bh, acc2[1][jn]);
        }
    }
    __syncthreads();   // done reading P

    // write ax_hi[32][256]bf16 @0, ax_lo @+16KB; byte = (q*512 + f*2) ^ ((q&7)<<4)
    #pragma unroll
    for (int qt = 0; qt < 2; ++qt)
        #pragma unroll
        for (int jn = 0; jn < 2; ++jn){
            int f = (wid*2 + jn)*16 + lr;
            #pragma unroll
            for (int r = 0; r < 4; ++r){
                int q = qt*16 + g*4 + r;
                float v = acc2[qt][jn][r];
                u16 h = f2bf(v);
                int byte = ((q<<9) + (f<<1)) ^ ((q&7)<<4);
                *(u16*)(sb + byte)         = h;
                *(u16*)(sb + 16384 + byte) = f2bf(v - bf2f(h));
            }
        }
    __syncthreads();   // ax ready

    // ---- Phase 4: out_pre = ax @ theta + thb via MFMA (B from THt, 1KB-coalesced)
    f32x4 acc3[2];
    acc3[0] = (f32x4){0.f,0.f,0.f,0.f};
    acc3[1] = (f32x4){0.f,0.f,0.f,0.f};
    int orow = wid*16 + lr;
    #pragma unroll
    for (int ks = 0; ks < 8; ++ks){
        int ab0 = ((lr<<9) + ks*64 + (g<<4)) ^ ((lr&7)<<4);
        bf16x8 a0h = *(const bf16x8*)(sb + ab0);
        bf16x8 a0l = *(const bf16x8*)(sb + 16384 + ab0);
        bf16x8 a1h = *(const bf16x8*)(sb + 8192 + ab0);
        bf16x8 a1l = *(const bf16x8*)(sb + 24576 + ab0);
        size_t tb = (size_t)ks*TH_FT + (size_t)orow*32 + g*8;
        bf16x8 bh = *(const bf16x8*)(THh + tb);
        bf16x8 bl = *(const bf16x8*)(THl + tb);
        acc3[0] = MFMA16(a0h, bh, acc3[0]);
        acc3[0] = MFMA16(a0h, bl, acc3[0]);
        acc3[0] = MFMA16(a0l, bh, acc3[0]);
        acc3[1] = MFMA16(a1h, bh, acc3[1]);
        acc3[1] = MFMA16(a1h, bl, acc3[1]);
        acc3[1] = MFMA16(a1l, bh, acc3[1]);
    }
    float tb2 = thb[orow];
    #pragma unroll
    for (int qt = 0; qt < 2; ++qt)
        #pragma unroll
        for (int r = 0; r < 4; ++r){
            int q = qt*16 + g*4 + r;
            size_t R = (size_t)bw*512 + tile*32 + q;
            outp[R*128 + orow] = acc3[qt][r] + tb2;
        }
}

// ---------------- BN1 stats over out_pre (deterministic two-stage)
__global__ __launch_bounds__(256) void k_stats1(const float* __restrict__ outp, float* __restrict__ part1){
    __shared__ float rs[256], rs2[256];
    int tid = threadIdx.x;
    int ch = tid & 127, rh = tid >> 7;
    size_t base = (size_t)blockIdx.x * 116;
    float s = 0.f, s2 = 0.f;
    for (int i = 0; i < 58; ++i){
        float v = outp[(base + rh + 2*i)*128 + ch];
        s += v; s2 += v*v;
    }
    rs[tid] = s; rs2[tid] = s2;
    __syncthreads();
    if (tid < 128){
        part1[blockIdx.x*256 + tid]       = rs[tid] + rs[tid+128];
        part1[blockIdx.x*256 + 128 + tid] = rs2[tid] + rs2[tid+128];
    }
}

__global__ __launch_bounds__(128) void k_fin1(const float* __restrict__ part1,
                                              const float* __restrict__ g1, const float* __restrict__ b1,
                                              float* __restrict__ sc1, float* __restrict__ sh1){
    int ch = threadIdx.x;
    float S = 0.f, S2 = 0.f;
    for (int b = 0; b < 1024; ++b){ S += part1[b*256 + ch]; S2 += part1[b*256 + 128 + ch]; }
    float mean = S / CNTF;
    float var  = S2 / CNTF - mean*mean;
    float sc = g1[ch] * rsqrtf(var + 1e-5f);
    sc1[ch] = sc;
    sh1[ch] = b1[ch] - mean*sc;
}

// ---------------- BN1 apply + leaky + mean-pool over tw
__global__ __launch_bounds__(256) void k_epi(const float* __restrict__ outp,
                                             const float* __restrict__ sc1, const float* __restrict__ sh1,
                                             float* __restrict__ out){
    int idx = blockIdx.x*256 + threadIdx.x;   // < 1900544
    int o = idx & 127;
    int rest = idx >> 7;
    int n = rest & 63;
    int bwq = rest >> 6;
    float sc = sc1[o], sh = sh1[o];
    size_t rowb = ((size_t)bwq*512 + n)*128 + o;
    float acc = 0.f;
    #pragma unroll
    for (int tw = 0; tw < 8; ++tw){
        float v = outp[rowb + (size_t)tw*64*128];
        v = v*sc + sh;
        v = (v > 0.f) ? v : 0.01f*v;
        acc += v;
    }
    out[idx] = acc * 0.125f;
}

extern "C" void kernel_launch(void* const* d_in, const int* in_sizes, int n_in,
                              void* d_out, int out_size, void* d_ws, size_t ws_size,
                              hipStream_t stream) {
    const float* x   = (const float*)d_in[0];
    const float* Wm  = (const float*)d_in[1];
    const float* bm  = (const float*)d_in[2];
    const float* g0  = (const float*)d_in[3];
    const float* b0  = (const float*)d_in[4];
    const float* th  = (const float*)d_in[5];
    const float* thb = (const float*)d_in[6];
    const float* g1  = (const float*)d_in[7];
    const float* b1  = (const float*)d_in[8];
    char* wsb  = (char*)d_ws;
    float* out = (float*)d_out;

    float* part = (float*)(wsb + B_PART);
    float* sc0  = (float*)(wsb + B_SC0);
    float* sh0  = (float*)(wsb + B_SH0);
    float* sc1  = (float*)(wsb + B_SC1);
    float* sh1  = (float*)(wsb + B_SH1);
    u16* Hh  = (u16*)(wsb + B_HH);
    u16* Hl  = (u16*)(wsb + B_HL);
    u16* XTh = (u16*)(wsb + B_XTH);
    u16* XTl = (u16*)(wsb + B_XTL);
    u16* THh = (u16*)(wsb + B_THH);
    u16* THl = (u16*)(wsb + B_THL);
    float* outp = (float*)(wsb + B_OUTP);

    hipLaunchKernelGGL(k_stats0, dim3(512),  dim3(256), 0, stream, x, part);
    hipLaunchKernelGGL(k_fin0,   dim3(1),    dim3(256), 0, stream, part, g0, b0, sc0, sh0);
    hipLaunchKernelGGL(k_prep,   dim3(128),  dim3(256), 0, stream, th, THh, THl);
    hipLaunchKernelGGL(k_map,    dim3(512),  dim3(256), 0, stream, x, Wm, bm, sc0, sh0, Hh, Hl, XTh, XTl);
    hipLaunchKernelGGL(k_attn,   dim3(3712), dim3(512), 0, stream, Hh, Hl, XTh, XTl, THh, THl, thb, outp);
    hipLaunchKernelGGL(k_stats1, dim3(1024), dim3(256), 0, stream, outp, part);
    hipLaunchKernelGGL(k_fin1,   dim3(1),    dim3(128), 0, stream, part, g1, b1, sc1, sh1);
    hipLaunchKernelGGL(k_epi,    dim3(7424), dim3(256), 0, stream, outp, sc1, sh1, out);
}